// Round 13
// baseline (2166.102 us; speedup 1.0000x reference)
//
#include <hip/hip_runtime.h>
#include <hip/hip_bf16.h>

typedef unsigned short u16;

#define NN 4096
#define SS 1024
#define NSAMP 32
#define NGRP 16384            // 16*1024 groups
#define ROWS 524288           // NGRP*NSAMP
#define BN_EPS_F 1e-5f
#define INV_ROWS (1.0f/524288.0f)

// ---------------- zero the 512-float stats block ----------------
__global__ void zero_kernel(float* p){
    p[threadIdx.x] = 0.0f;   // launched with 512 threads
}

// ---------------- column reduce: dst[c] = sum_b part[b][c] (no atomics) ----------------
__global__ void reduce_kernel(const float* __restrict__ part, int nblk, int ncol,
                              float* __restrict__ dst){
    int c = threadIdx.x;
    if (c >= ncol) return;
    float s0=0.f,s1=0.f,s2=0.f,s3=0.f,s4=0.f,s5=0.f,s6=0.f,s7=0.f;
    for (int b = 0; b < nblk; b += 8){   // 8 independent accumulators: keep loads in flight
        s0 += part[(size_t)(b+0)*ncol + c];
        s1 += part[(size_t)(b+1)*ncol + c];
        s2 += part[(size_t)(b+2)*ncol + c];
        s3 += part[(size_t)(b+3)*ncol + c];
        s4 += part[(size_t)(b+4)*ncol + c];
        s5 += part[(size_t)(b+5)*ncol + c];
        s6 += part[(size_t)(b+6)*ncol + c];
        s7 += part[(size_t)(b+7)*ncol + c];
    }
    dst[c] = ((s0+s1)+(s2+s3)) + ((s4+s5)+(s6+s7));
}

// ---------------- FPS v7 (660us plateau): DPP wave-reduce ----------------
// Key = (distbits<<32)|(NN-1-idx): exact argmax with first-index tie-break.
#define FPS_DPP_STEP(CTRL)                                                              \
    {   int hs = __builtin_amdgcn_update_dpp((int)(bk >> 32), (int)(bk >> 32),          \
                                             CTRL, 0xf, 0xf, false);                    \
        int ls = __builtin_amdgcn_update_dpp((int)bk, (int)bk, CTRL, 0xf, 0xf, false);  \
        unsigned long long o = ((unsigned long long)(unsigned int)hs << 32)             \
                               | (unsigned int)ls;                                      \
        bk = bk > o ? bk : o; }

__global__ __launch_bounds__(256, 1) void fps_kernel(const float* __restrict__ xyz,
                                                     float* __restrict__ out){
    __shared__ float xs[NN], ys[NN], zs[NN];
    __shared__ unsigned long long red[2][4];
    const int b = blockIdx.x;
    const int tid = threadIdx.x;
    const float* xb = xyz + (size_t)b * NN * 3;
    float px[16], py[16], pz[16], dreg[16];
    unsigned int inv[16];
    #pragma unroll
    for (int p = 0; p < 16; ++p){
        int i = tid + p * 256;
        float x = xb[i*3+0], y = xb[i*3+1], z = xb[i*3+2];
        px[p] = x; py[p] = y; pz[p] = z;
        xs[i] = x; ys[i] = y; zs[i] = z;
        dreg[p] = 1e10f;                      // ref init 1e10 (exact f32)
        inv[p] = (unsigned int)(NN - 1 - i);  // loop-invariant key low word
    }
    int cur = 0;
    __syncthreads();
    if (tid == 0){  // fps_idx[b,0] == 0 (scan emits carry before update)
        float* of = out + (size_t)b * SS * 3;
        of[0] = xs[0]; of[1] = ys[0]; of[2] = zs[0];
    }
    const int wave = tid >> 6, lane = tid & 63;
    for (int it = 1; it < SS; ++it){
        float cx = xs[cur], cy = ys[cur], cz = zs[cur];   // uniform LDS broadcast
        unsigned long long t[16];
        // strict fp32, no fma contraction: must match numpy's ((dx*dx+dy*dy)+dz*dz) bitwise
        #pragma unroll
        for (int p = 0; p < 16; ++p){
            float dx = __fsub_rn(px[p], cx);
            float dy = __fsub_rn(py[p], cy);
            float dz = __fsub_rn(pz[p], cz);
            float dd = __fadd_rn(__fadd_rn(__fmul_rn(dx,dx), __fmul_rn(dy,dy)),
                                 __fmul_rn(dz,dz));
            dreg[p] = fminf(dreg[p], dd);
            t[p] = ((unsigned long long)__float_as_uint(dreg[p]) << 32) | inv[p];
        }
        // pairwise tree (ILP) instead of serial 16-deep chain
        #pragma unroll
        for (int s = 8; s >= 1; s >>= 1)
            #pragma unroll
            for (int i2 = 0; i2 < s; ++i2)
                if (t[i2 + s] > t[i2]) t[i2] = t[i2 + s];
        unsigned long long bk = t[0];
        // DPP reduce over 64 lanes -> winner at lane 63 (VALU pipe, no DS latency)
        FPS_DPP_STEP(0x111)  // row_shr:1
        FPS_DPP_STEP(0x112)  // row_shr:2
        FPS_DPP_STEP(0x114)  // row_shr:4
        FPS_DPP_STEP(0x118)  // row_shr:8  -> lane15 of each row = row max
        FPS_DPP_STEP(0x142)  // row_bcast:15 -> lane31/63 accumulate halves
        FPS_DPP_STEP(0x143)  // row_bcast:31 -> lane63 = wave max
        unsigned int wh = (unsigned int)__builtin_amdgcn_readlane((int)(bk >> 32), 63);
        unsigned int wl = (unsigned int)__builtin_amdgcn_readlane((int)bk, 63);
        if (lane == 0) red[it & 1][wave] = ((unsigned long long)wh << 32) | wl;
        __syncthreads();                       // double-buffered red: one barrier/iter
        unsigned long long m0 = red[it & 1][0];
        #pragma unroll
        for (int w = 1; w < 4; ++w){
            unsigned long long o = red[it & 1][w];
            m0 = m0 > o ? m0 : o;
        }
        cur = (NN - 1 - (int)(m0 & 0xffffffffu)) & (NN - 1);
        if (tid == 0){
            float* of = out + ((size_t)b * SS + it) * 3;
            of[0] = xs[cur]; of[1] = ys[cur]; of[2] = zs[cur];
        }
    }
}

// ---------------- ball query v2: 128 pts/iter ----------------
__global__ __launch_bounds__(256) void ballq_kernel(const float* __restrict__ xyz,
                                                    const float* __restrict__ outc,
                                                    u16* __restrict__ gidx){
    const int g = (blockIdx.x << 2) + (threadIdx.x >> 6);
    const int lane = threadIdx.x & 63;
    const int b = g >> 10;
    const float rr = 0.04f;   // np.float32 promotion of python 0.2*0.2
    const float* c = outc + (size_t)g * 3;
    float cx = c[0], cy = c[1], cz = c[2];
    float sa = __fadd_rn(__fadd_rn(__fmul_rn(cx,cx), __fmul_rn(cy,cy)), __fmul_rn(cz,cz));
    const float* xb = xyz + (size_t)b * NN * 3;
    u16* outp = gidx + (size_t)g * NSAMP;
    int count = 0, first = -1;
    const unsigned long long below = (1ull << lane) - 1ull;
    for (int base = 0; base < NN && count < NSAMP; base += 128){
        int n1 = base + lane, n2 = base + 64 + lane;
        float x1 = xb[n1*3+0], y1 = xb[n1*3+1], z1 = xb[n1*3+2];
        float x2 = xb[n2*3+0], y2 = xb[n2*3+1], z2 = xb[n2*3+2];
        // reference: sum(a^2) - 2*dot + sum(b^2), fp32, no contraction
        float sb1 = __fadd_rn(__fadd_rn(__fmul_rn(x1,x1), __fmul_rn(y1,y1)), __fmul_rn(z1,z1));
        float dt1 = __fadd_rn(__fadd_rn(__fmul_rn(cx,x1), __fmul_rn(cy,y1)), __fmul_rn(cz,z1));
        float sq1 = __fadd_rn(__fsub_rn(sa, __fmul_rn(2.0f, dt1)), sb1);
        float sb2 = __fadd_rn(__fadd_rn(__fmul_rn(x2,x2), __fmul_rn(y2,y2)), __fmul_rn(z2,z2));
        float dt2 = __fadd_rn(__fadd_rn(__fmul_rn(cx,x2), __fmul_rn(cy,y2)), __fmul_rn(cz,z2));
        float sq2 = __fadd_rn(__fsub_rn(sa, __fmul_rn(2.0f, dt2)), sb2);
        bool w1 = !(sq1 > rr), w2 = !(sq2 > rr);
        unsigned long long m1 = __ballot(w1);
        unsigned long long m2 = __ballot(w2);
        int pos1 = __popcll(m1 & below);
        if (w1 && (count + pos1) < NSAMP) outp[count + pos1] = (u16)n1;
        int c1 = count + __popcll(m1);
        int pos2 = __popcll(m2 & below);
        if (w2 && (c1 + pos2) < NSAMP) outp[c1 + pos2] = (u16)n2;
        if (first < 0){
            if (m1) first = base + (__ffsll((long long)m1) - 1);
            else if (m2) first = base + 64 + (__ffsll((long long)m2) - 1);
        }
        count = c1 + __popcll(m2);
    }
    for (int j = count + lane; j < NSAMP; j += 64) outp[j] = (u16)first;
}

// ---------------- shared helpers ----------------
__device__ __forceinline__ void gather_row(const float* __restrict__ xyz, const float* __restrict__ pts,
                                           const float* __restrict__ outc, const u16* __restrict__ gidx,
                                           int row, float* x){
    int g = row >> 5;
    int b = row >> 15;
    int i = gidx[row];
    const float* cc = outc + (size_t)g * 3;
    const float* xp = xyz + ((size_t)b * NN + i) * 3;
    const float* pp = pts + ((size_t)b * NN + i) * 6;
    x[0] = __fsub_rn(xp[0], cc[0]);
    x[1] = __fsub_rn(xp[1], cc[1]);
    x[2] = __fsub_rn(xp[2], cc[2]);
    #pragma unroll
    for (int k = 0; k < 6; ++k) x[3+k] = pp[k];
}

__device__ __forceinline__ void bn_coef(const float* sums, const float* ssqs,
                                        const float* g, const float* bbv, int ch,
                                        float* sc, float* sh){
    float mu = sums[ch] * INV_ROWS;
    float var = fmaf(-mu, mu, ssqs[ch] * INV_ROWS);
    var = fmaxf(var, 0.0f);
    float is = rsqrtf(var + BN_EPS_F);
    float s = is * g[ch];
    sc[ch] = s;
    sh[ch] = fmaf(-mu, s, bbv[ch]);
}

// ---------------- stats1: sums/ssq of h1 (layer-1 pre-BN); 256 blocks, few atomics ----------------
__global__ __launch_bounds__(256, 1) void stats1_kernel(const float* __restrict__ xyz, const float* __restrict__ pts,
                                                        const float* __restrict__ outc, const u16* __restrict__ gidx,
                                                        const float* __restrict__ W0f, const float* __restrict__ b0f,
                                                        float* __restrict__ stats){
    float s[64], q[64];
    #pragma unroll
    for (int j = 0; j < 64; ++j){ s[j] = 0.f; q[j] = 0.f; }
    int base = blockIdx.x * 2048 + threadIdx.x;
    for (int r = 0; r < 8; ++r){
        float x[9];
        gather_row(xyz, pts, outc, gidx, base + r*256, x);
        #pragma unroll
        for (int j = 0; j < 64; ++j){
            float acc = b0f[j];
            #pragma unroll
            for (int k = 0; k < 9; ++k) acc = fmaf(x[k], W0f[j*9+k], acc);
            s[j] += acc; q[j] = fmaf(acc, acc, q[j]);
        }
    }
    #pragma unroll
    for (int j = 0; j < 64; ++j){
        #pragma unroll
        for (int off = 1; off < 64; off <<= 1){
            s[j] += __shfl_xor(s[j], off, 64);
            q[j] += __shfl_xor(q[j], off, 64);
        }
    }
    if ((threadIdx.x & 63) == 0){
        #pragma unroll
        for (int j = 0; j < 64; ++j){
            atomicAdd(&stats[j], s[j]);
            atomicAdd(&stats[64 + j], q[j]);
        }
    }
}

// ---------------- stats2: transpose reduce -> per-block partials (NO global atomics) ----------------
__global__ __launch_bounds__(256, 1) void stats2_kernel(const float* __restrict__ xyz, const float* __restrict__ pts,
                                                        const float* __restrict__ outc, const u16* __restrict__ gidx,
                                                        const float* __restrict__ W0f, const float* __restrict__ b0f,
                                                        const float* __restrict__ W1f, const float* __restrict__ b1f,
                                                        const float* __restrict__ g0, const float* __restrict__ bb0,
                                                        const float* __restrict__ stats,
                                                        float* __restrict__ part2){
    __shared__ float sc1[64], sh1[64];
    __shared__ float tr[256 * 65];
    __shared__ float accs[4][64], accq[4][64];
    if (threadIdx.x < 64) bn_coef(stats + 0, stats + 64, g0, bb0, threadIdx.x, sc1, sh1);
    __syncthreads();
    const int row = blockIdx.x * 256 + threadIdx.x;
    float x[9];
    gather_row(xyz, pts, outc, gidx, row, x);
    float x2[64];
    #pragma unroll
    for (int j = 0; j < 64; ++j){
        float acc = b0f[j];
        #pragma unroll
        for (int k = 0; k < 9; ++k) acc = fmaf(x[k], W0f[j*9+k], acc);
        x2[j] = fmaxf(fmaf(acc, sc1[j], sh1[j]), 0.f);
    }
    for (int ch = 0; ch < 64; ++ch){
        float a0 = b1f[ch], a1 = 0.f, a2 = 0.f, a3 = 0.f;
        const float* wrow = W1f + ch * 64;
        #pragma unroll
        for (int k = 0; k < 64; k += 4){
            a0 = fmaf(x2[k+0], wrow[k+0], a0);
            a1 = fmaf(x2[k+1], wrow[k+1], a1);
            a2 = fmaf(x2[k+2], wrow[k+2], a2);
            a3 = fmaf(x2[k+3], wrow[k+3], a3);
        }
        tr[threadIdx.x * 65 + ch] = (a0 + a1) + (a2 + a3);
    }
    __syncthreads();
    const int ch = threadIdx.x & 63, qq = threadIdx.x >> 6;
    float s = 0.f, q = 0.f;
    for (int r = 0; r < 64; ++r){
        float v = tr[(qq * 64 + r) * 65 + ch];
        s += v; q = fmaf(v, v, q);
    }
    accs[qq][ch] = s; accq[qq][ch] = q;
    __syncthreads();
    if (threadIdx.x < 64){
        int c = threadIdx.x;
        part2[(size_t)blockIdx.x * 128 + c] = (accs[0][c] + accs[1][c]) + (accs[2][c] + accs[3][c]);
    } else if (threadIdx.x < 128){
        int c = threadIdx.x - 64;
        part2[(size_t)blockIdx.x * 128 + 64 + c] = (accq[0][c] + accq[1][c]) + (accq[2][c] + accq[3][c]);
    }
}

// ---------------- stats3: full chain; partials (NO global atomics); pmax -> d_out region1 ----------------
__global__ __launch_bounds__(256, 1) void stats3_kernel(const float* __restrict__ xyz, const float* __restrict__ pts,
                                                        const float* __restrict__ outc, const u16* __restrict__ gidx,
                                                        const float* __restrict__ W0f, const float* __restrict__ b0f,
                                                        const float* __restrict__ W1f, const float* __restrict__ b1f,
                                                        const float* __restrict__ W2f, const float* __restrict__ b2f,
                                                        const float* __restrict__ g0, const float* __restrict__ bb0,
                                                        const float* __restrict__ g1, const float* __restrict__ bb1,
                                                        const float* __restrict__ stats,
                                                        float* __restrict__ part3,
                                                        float* __restrict__ pmax, float* __restrict__ pmin){
    __shared__ float sc1[64], sh1[64], sc2[64], sh2[64];
    __shared__ float tr[256 * 65];
    __shared__ float accs[4][64], accq[4][64];
    if (threadIdx.x < 64){
        bn_coef(stats + 0,   stats + 64,  g0, bb0, threadIdx.x, sc1, sh1);
        bn_coef(stats + 128, stats + 192, g1, bb1, threadIdx.x, sc2, sh2);
    }
    __syncthreads();
    const int row = blockIdx.x * 256 + threadIdx.x;
    float x[9];
    gather_row(xyz, pts, outc, gidx, row, x);
    float x2[64];
    #pragma unroll
    for (int j = 0; j < 64; ++j){
        float acc = b0f[j];
        #pragma unroll
        for (int k = 0; k < 9; ++k) acc = fmaf(x[k], W0f[j*9+k], acc);
        x2[j] = fmaxf(fmaf(acc, sc1[j], sh1[j]), 0.f);
    }
    float x3[64];
    #pragma unroll
    for (int j = 0; j < 64; ++j){
        float a0 = b1f[j], a1 = 0.f, a2 = 0.f, a3 = 0.f;
        const float* wrow = W1f + j * 64;
        #pragma unroll
        for (int k = 0; k < 64; k += 4){
            a0 = fmaf(x2[k+0], wrow[k+0], a0);
            a1 = fmaf(x2[k+1], wrow[k+1], a1);
            a2 = fmaf(x2[k+2], wrow[k+2], a2);
            a3 = fmaf(x2[k+3], wrow[k+3], a3);
        }
        x3[j] = fmaxf(fmaf((a0 + a1) + (a2 + a3), sc2[j], sh2[j]), 0.f);
    }
    const int ch = threadIdx.x & 63, qq = threadIdx.x >> 6;
    for (int half = 0; half < 2; ++half){
        for (int c64 = 0; c64 < 64; ++c64){
            int c = half * 64 + c64;
            float a0 = b2f[c], a1 = 0.f, a2 = 0.f, a3 = 0.f;
            const float* wrow = W2f + c * 64;
            #pragma unroll
            for (int k = 0; k < 64; k += 4){
                a0 = fmaf(x3[k+0], wrow[k+0], a0);
                a1 = fmaf(x3[k+1], wrow[k+1], a1);
                a2 = fmaf(x3[k+2], wrow[k+2], a2);
                a3 = fmaf(x3[k+3], wrow[k+3], a3);
            }
            tr[threadIdx.x * 65 + c64] = (a0 + a1) + (a2 + a3);
        }
        __syncthreads();
        // quarter qq = rows [qq*64, qq*64+64) = groups 2qq (first 32 rows) and 2qq+1
        float s = 0.f, q = 0.f;
        float mxA = -1e30f, mnA = 1e30f, mxB = -1e30f, mnB = 1e30f;
        for (int r = 0; r < 32; ++r){
            float v = tr[(qq * 64 + r) * 65 + ch];
            s += v; q = fmaf(v, v, q);
            mxA = fmaxf(mxA, v); mnA = fminf(mnA, v);
        }
        for (int r = 32; r < 64; ++r){
            float v = tr[(qq * 64 + r) * 65 + ch];
            s += v; q = fmaf(v, v, q);
            mxB = fmaxf(mxB, v); mnB = fminf(mnB, v);
        }
        int c = half * 64 + ch;
        int gA = blockIdx.x * 8 + 2 * qq;
        pmax[(size_t)gA * 128 + c] = mxA;           // coalesced across lanes (c consecutive)
        pmin[(size_t)gA * 128 + c] = mnA;
        pmax[(size_t)(gA + 1) * 128 + c] = mxB;
        pmin[(size_t)(gA + 1) * 128 + c] = mnB;
        accs[qq][ch] = s; accq[qq][ch] = q;
        __syncthreads();
        if (threadIdx.x < 64){
            int cc = half * 64 + threadIdx.x;
            part3[(size_t)blockIdx.x * 256 + cc] = (accs[0][threadIdx.x] + accs[1][threadIdx.x])
                                                 + (accs[2][threadIdx.x] + accs[3][threadIdx.x]);
        } else if (threadIdx.x < 128){
            int t = threadIdx.x - 64;
            int cc = half * 64 + t;
            part3[(size_t)blockIdx.x * 256 + 128 + cc] = (accq[0][t] + accq[1][t]) + (accq[2][t] + accq[3][t]);
        }
        __syncthreads();   // tr + accs reuse protection for next half
    }
}

// ---------------- BN3 on group max/min, relu; pmax lives in out region1 (overwritten in place) ----------------
__global__ __launch_bounds__(256) void pool_kernel(const float* __restrict__ stats,
                                                   const float* __restrict__ g2, const float* __restrict__ bb2,
                                                   const float* __restrict__ pmin,
                                                   float* __restrict__ out){
    __shared__ float sc[128], sh[128];
    if (threadIdx.x < 128) bn_coef(stats + 256, stats + 384, g2, bb2, threadIdx.x, sc, sh);
    __syncthreads();
    int o = blockIdx.x * 256 + threadIdx.x;   // o = g*128 + ch, o < NGRP*128
    int ch = o & 127;
    float pm = out[NGRP * 3 + o];             // pmax staged here by stats3
    float a = fmaf(pm, sc[ch], sh[ch]);
    float b = fmaf(pmin[o], sc[ch], sh[ch]);  // affine maps interval endpoints (sc<0 covered)
    out[NGRP * 3 + o] = fmaxf(fmaxf(a, b), 0.0f);
}

extern "C" void kernel_launch(void* const* d_in, const int* in_sizes, int n_in,
                              void* d_out, int out_size, void* d_ws, size_t ws_size,
                              hipStream_t stream){
    const float* xyz = (const float*)d_in[0];
    const float* pts = (const float*)d_in[1];
    const float* W0  = (const float*)d_in[2];
    const float* b0  = (const float*)d_in[3];
    const float* g0  = (const float*)d_in[4];
    const float* bb0 = (const float*)d_in[5];
    const float* W1  = (const float*)d_in[6];
    const float* b1  = (const float*)d_in[7];
    const float* g1  = (const float*)d_in[8];
    const float* bb1 = (const float*)d_in[9];
    const float* W2  = (const float*)d_in[10];
    const float* b2  = (const float*)d_in[11];
    const float* g2  = (const float*)d_in[12];
    const float* bb2 = (const float*)d_in[13];
    float* out = (float*)d_out;   // f32: [new_xyz 49152 | new_points 2097152]; region1 doubles as pmax staging

    // ws layout (bytes): stats[512f]@0 | gidx[524288 u16]@2048 | pmin[2097152f]@1050624 |
    //                    part2[2048*128f]@9439232 | part3[2048*256f]@10487808 ; total 12,584,960
    if (ws_size < 12584960u) return;
    char*  ws    = (char*)d_ws;
    float* stats = (float*)ws;
    u16*   gidx  = (u16*)  (ws + 2048);
    float* pmin  = (float*)(ws + 1050624);
    float* part2 = (float*)(ws + 9439232);
    float* part3 = (float*)(ws + 10487808);
    float* pmax  = out + NGRP * 3;

    zero_kernel <<<1, 512, 0, stream>>>(stats);
    fps_kernel  <<<16, 256, 0, stream>>>(xyz, out);
    ballq_kernel<<<NGRP/4, 256, 0, stream>>>(xyz, out, gidx);
    stats1_kernel<<<256, 256, 0, stream>>>(xyz, pts, out, gidx, W0, b0, stats);
    stats2_kernel<<<ROWS/256, 256, 0, stream>>>(xyz, pts, out, gidx, W0, b0, W1, b1, g0, bb0,
                                                stats, part2);
    reduce_kernel<<<1, 128, 0, stream>>>(part2, ROWS/256, 128, stats + 128);
    stats3_kernel<<<ROWS/256, 256, 0, stream>>>(xyz, pts, out, gidx, W0, b0, W1, b1, W2, b2,
                                                g0, bb0, g1, bb1, stats, part3, pmax, pmin);
    reduce_kernel<<<1, 256, 0, stream>>>(part3, ROWS/256, 256, stats + 256);
    pool_kernel <<<NGRP*128/256, 256, 0, stream>>>(stats, g2, bb2, pmin, out);
}

// Round 14
// 1378.445 us; speedup vs baseline: 1.5714x; 1.5714x over previous
//
#include <hip/hip_runtime.h>
#include <hip/hip_bf16.h>

typedef unsigned short u16;

#define NN 4096
#define SS 1024
#define NSAMP 32
#define NGRP 16384            // 16*1024 groups
#define ROWS 524288           // NGRP*NSAMP
#define BN_EPS_F 1e-5f
#define INV_ROWS (1.0f/524288.0f)

// ---------------- zero the 512-float stats block ----------------
__global__ void zero_kernel(float* p){
    p[threadIdx.x] = 0.0f;   // launched with 512 threads
}

// ---------------- FPS v7 (660us plateau): DPP wave-reduce ----------------
// Key = (distbits<<32)|(NN-1-idx): exact argmax with first-index tie-break.
#define FPS_DPP_STEP(CTRL)                                                              \
    {   int hs = __builtin_amdgcn_update_dpp((int)(bk >> 32), (int)(bk >> 32),          \
                                             CTRL, 0xf, 0xf, false);                    \
        int ls = __builtin_amdgcn_update_dpp((int)bk, (int)bk, CTRL, 0xf, 0xf, false);  \
        unsigned long long o = ((unsigned long long)(unsigned int)hs << 32)             \
                               | (unsigned int)ls;                                      \
        bk = bk > o ? bk : o; }

__global__ __launch_bounds__(256, 1) void fps_kernel(const float* __restrict__ xyz,
                                                     float* __restrict__ out){
    __shared__ float xs[NN], ys[NN], zs[NN];
    __shared__ unsigned long long red[2][4];
    const int b = blockIdx.x;
    const int tid = threadIdx.x;
    const float* xb = xyz + (size_t)b * NN * 3;
    float px[16], py[16], pz[16], dreg[16];
    unsigned int inv[16];
    #pragma unroll
    for (int p = 0; p < 16; ++p){
        int i = tid + p * 256;
        float x = xb[i*3+0], y = xb[i*3+1], z = xb[i*3+2];
        px[p] = x; py[p] = y; pz[p] = z;
        xs[i] = x; ys[i] = y; zs[i] = z;
        dreg[p] = 1e10f;                      // ref init 1e10 (exact f32)
        inv[p] = (unsigned int)(NN - 1 - i);  // loop-invariant key low word
    }
    int cur = 0;
    __syncthreads();
    if (tid == 0){  // fps_idx[b,0] == 0 (scan emits carry before update)
        float* of = out + (size_t)b * SS * 3;
        of[0] = xs[0]; of[1] = ys[0]; of[2] = zs[0];
    }
    const int wave = tid >> 6, lane = tid & 63;
    for (int it = 1; it < SS; ++it){
        float cx = xs[cur], cy = ys[cur], cz = zs[cur];   // uniform LDS broadcast
        unsigned long long t[16];
        // strict fp32, no fma contraction: must match numpy's ((dx*dx+dy*dy)+dz*dz) bitwise
        #pragma unroll
        for (int p = 0; p < 16; ++p){
            float dx = __fsub_rn(px[p], cx);
            float dy = __fsub_rn(py[p], cy);
            float dz = __fsub_rn(pz[p], cz);
            float dd = __fadd_rn(__fadd_rn(__fmul_rn(dx,dx), __fmul_rn(dy,dy)),
                                 __fmul_rn(dz,dz));
            dreg[p] = fminf(dreg[p], dd);
            t[p] = ((unsigned long long)__float_as_uint(dreg[p]) << 32) | inv[p];
        }
        // pairwise tree (ILP) instead of serial 16-deep chain
        #pragma unroll
        for (int s = 8; s >= 1; s >>= 1)
            #pragma unroll
            for (int i2 = 0; i2 < s; ++i2)
                if (t[i2 + s] > t[i2]) t[i2] = t[i2 + s];
        unsigned long long bk = t[0];
        // DPP reduce over 64 lanes -> winner at lane 63 (VALU pipe, no DS latency)
        FPS_DPP_STEP(0x111)  // row_shr:1
        FPS_DPP_STEP(0x112)  // row_shr:2
        FPS_DPP_STEP(0x114)  // row_shr:4
        FPS_DPP_STEP(0x118)  // row_shr:8  -> lane15 of each row = row max
        FPS_DPP_STEP(0x142)  // row_bcast:15 -> lane31/63 accumulate halves
        FPS_DPP_STEP(0x143)  // row_bcast:31 -> lane63 = wave max
        unsigned int wh = (unsigned int)__builtin_amdgcn_readlane((int)(bk >> 32), 63);
        unsigned int wl = (unsigned int)__builtin_amdgcn_readlane((int)bk, 63);
        if (lane == 0) red[it & 1][wave] = ((unsigned long long)wh << 32) | wl;
        __syncthreads();                       // double-buffered red: one barrier/iter
        unsigned long long m0 = red[it & 1][0];
        #pragma unroll
        for (int w = 1; w < 4; ++w){
            unsigned long long o = red[it & 1][w];
            m0 = m0 > o ? m0 : o;
        }
        cur = (NN - 1 - (int)(m0 & 0xffffffffu)) & (NN - 1);
        if (tid == 0){
            float* of = out + ((size_t)b * SS + it) * 3;
            of[0] = xs[cur]; of[1] = ys[cur]; of[2] = zs[cur];
        }
    }
}

// ---------------- ball query v3: 512-pt super-chunks, pipelined masks ----------------
// v1/v2 serialized: per-64-chunk loads waited behind the early-exit branch (~300cyc L2
// latency x 15-64 iters). v3 computes 8 independent ballots (loads all in flight), then
// a VALU-only append. Semantics bit-identical: ascending index append, first-hit fill.
__global__ __launch_bounds__(256) void ballq_kernel(const float* __restrict__ xyz,
                                                    const float* __restrict__ outc,
                                                    u16* __restrict__ gidx){
    const int g = (blockIdx.x << 2) + (threadIdx.x >> 6);
    const int lane = threadIdx.x & 63;
    const int b = g >> 10;
    const float rr = 0.04f;   // np.float32 promotion of python 0.2*0.2
    const float* c = outc + (size_t)g * 3;
    float cx = c[0], cy = c[1], cz = c[2];
    float sa = __fadd_rn(__fadd_rn(__fmul_rn(cx,cx), __fmul_rn(cy,cy)), __fmul_rn(cz,cz));
    const float* xb = xyz + (size_t)b * NN * 3;
    u16* outp = gidx + (size_t)g * NSAMP;
    int count = 0, first = -1;
    const unsigned long long below = (1ull << lane) - 1ull;
    for (int base = 0; base < NN && count < NSAMP; base += 512){
        unsigned long long masks[8];
        #pragma unroll
        for (int u = 0; u < 8; ++u){          // 8 independent distance+ballot: loads pipeline
            int n = base + u * 64 + lane;
            float x = xb[n*3+0], y = xb[n*3+1], z = xb[n*3+2];
            // reference: sum(a^2) - 2*dot + sum(b^2), fp32, no contraction
            float sb = __fadd_rn(__fadd_rn(__fmul_rn(x,x), __fmul_rn(y,y)), __fmul_rn(z,z));
            float dt = __fadd_rn(__fadd_rn(__fmul_rn(cx,x), __fmul_rn(cy,y)), __fmul_rn(cz,z));
            float sq = __fadd_rn(__fsub_rn(sa, __fmul_rn(2.0f, dt)), sb);
            masks[u] = __ballot(!(sq > rr));
        }
        #pragma unroll
        for (int u = 0; u < 8; ++u){          // append phase: VALU-only serial chain
            unsigned long long m = masks[u];
            bool w = (m >> lane) & 1ull;
            int pos = __popcll(m & below);
            if (w && (count + pos) < NSAMP) outp[count + pos] = (u16)(base + u * 64 + lane);
            if (first < 0 && m != 0ull) first = base + u * 64 + (__ffsll((long long)m) - 1);
            count += __popcll(m);
        }
    }
    for (int j = count + lane; j < NSAMP; j += 64) outp[j] = (u16)first;
}

// ---------------- shared helpers ----------------
__device__ __forceinline__ void gather_row(const float* __restrict__ xyz, const float* __restrict__ pts,
                                           const float* __restrict__ outc, const u16* __restrict__ gidx,
                                           int row, float* x){
    int g = row >> 5;
    int b = row >> 15;
    int i = gidx[row];
    const float* cc = outc + (size_t)g * 3;
    const float* xp = xyz + ((size_t)b * NN + i) * 3;
    const float* pp = pts + ((size_t)b * NN + i) * 6;
    x[0] = __fsub_rn(xp[0], cc[0]);
    x[1] = __fsub_rn(xp[1], cc[1]);
    x[2] = __fsub_rn(xp[2], cc[2]);
    #pragma unroll
    for (int k = 0; k < 6; ++k) x[3+k] = pp[k];
}

__device__ __forceinline__ void bn_coef(const float* sums, const float* ssqs,
                                        const float* g, const float* bbv, int ch,
                                        float* sc, float* sh){
    float mu = sums[ch] * INV_ROWS;
    float var = fmaf(-mu, mu, ssqs[ch] * INV_ROWS);
    var = fmaxf(var, 0.0f);
    float is = rsqrtf(var + BN_EPS_F);
    float s = is * g[ch];
    sc[ch] = s;
    sh[ch] = fmaf(-mu, s, bbv[ch]);
}

// ---------------- stats1 v2: one row/thread + LDS-transpose reduce ----------------
// v1 (unchanged since R5!) had s[64]/q[64] arrays (VGPR 136 -> partial spill) + 768
// dependent ds_swizzles/wave -- the same disease that made stats2-v1 cost ~600us.
__global__ __launch_bounds__(256, 1) void stats1_kernel(const float* __restrict__ xyz, const float* __restrict__ pts,
                                                        const float* __restrict__ outc, const u16* __restrict__ gidx,
                                                        const float* __restrict__ W0f, const float* __restrict__ b0f,
                                                        float* __restrict__ stats){
    __shared__ float tr[256 * 65];
    __shared__ float accs[4][64], accq[4][64];
    const int row = blockIdx.x * 256 + threadIdx.x;
    float x[9];
    gather_row(xyz, pts, outc, gidx, row, x);
    #pragma unroll
    for (int j = 0; j < 64; ++j){
        float acc = b0f[j];
        #pragma unroll
        for (int k = 0; k < 9; ++k) acc = fmaf(x[k], W0f[j*9+k], acc);
        tr[threadIdx.x * 65 + j] = acc;
    }
    __syncthreads();
    const int ch = threadIdx.x & 63, qq = threadIdx.x >> 6;
    float s = 0.f, q = 0.f;
    for (int r = 0; r < 64; ++r){
        float v = tr[(qq * 64 + r) * 65 + ch];
        s += v; q = fmaf(v, v, q);
    }
    accs[qq][ch] = s; accq[qq][ch] = q;
    __syncthreads();
    if (threadIdx.x < 64){
        int c = threadIdx.x;
        atomicAdd(&stats[c], (accs[0][c] + accs[1][c]) + (accs[2][c] + accs[3][c]));
    } else if (threadIdx.x < 128){
        int c = threadIdx.x - 64;
        atomicAdd(&stats[64 + c], (accq[0][c] + accq[1][c]) + (accq[2][c] + accq[3][c]));
    }
}

// ---------------- stats2: transpose reduce + (256,1)  [R12 verbatim] ----------------
__global__ __launch_bounds__(256, 1) void stats2_kernel(const float* __restrict__ xyz, const float* __restrict__ pts,
                                                        const float* __restrict__ outc, const u16* __restrict__ gidx,
                                                        const float* __restrict__ W0f, const float* __restrict__ b0f,
                                                        const float* __restrict__ W1f, const float* __restrict__ b1f,
                                                        const float* __restrict__ g0, const float* __restrict__ bb0,
                                                        float* __restrict__ stats){
    __shared__ float sc1[64], sh1[64];
    __shared__ float tr[256 * 65];
    __shared__ float accs[4][64], accq[4][64];
    if (threadIdx.x < 64) bn_coef(stats + 0, stats + 64, g0, bb0, threadIdx.x, sc1, sh1);
    __syncthreads();
    const int row = blockIdx.x * 256 + threadIdx.x;
    float x[9];
    gather_row(xyz, pts, outc, gidx, row, x);
    float x2[64];
    #pragma unroll
    for (int j = 0; j < 64; ++j){
        float acc = b0f[j];
        #pragma unroll
        for (int k = 0; k < 9; ++k) acc = fmaf(x[k], W0f[j*9+k], acc);
        x2[j] = fmaxf(fmaf(acc, sc1[j], sh1[j]), 0.f);
    }
    for (int ch = 0; ch < 64; ++ch){
        float a0 = b1f[ch], a1 = 0.f, a2 = 0.f, a3 = 0.f;
        const float* wrow = W1f + ch * 64;
        #pragma unroll
        for (int k = 0; k < 64; k += 4){
            a0 = fmaf(x2[k+0], wrow[k+0], a0);
            a1 = fmaf(x2[k+1], wrow[k+1], a1);
            a2 = fmaf(x2[k+2], wrow[k+2], a2);
            a3 = fmaf(x2[k+3], wrow[k+3], a3);
        }
        tr[threadIdx.x * 65 + ch] = (a0 + a1) + (a2 + a3);
    }
    __syncthreads();
    const int ch = threadIdx.x & 63, qq = threadIdx.x >> 6;
    float s = 0.f, q = 0.f;
    for (int r = 0; r < 64; ++r){
        float v = tr[(qq * 64 + r) * 65 + ch];
        s += v; q = fmaf(v, v, q);
    }
    accs[qq][ch] = s; accq[qq][ch] = q;
    __syncthreads();
    if (threadIdx.x < 64){
        int c = threadIdx.x;
        atomicAdd(&stats[128 + c], (accs[0][c] + accs[1][c]) + (accs[2][c] + accs[3][c]));
    } else if (threadIdx.x < 128){
        int c = threadIdx.x - 64;
        atomicAdd(&stats[192 + c], (accq[0][c] + accq[1][c]) + (accq[2][c] + accq[3][c]));
    }
}

// ---------------- stats3: full chain; transpose reduce, two 64-ch halves  [R12 verbatim] ----------------
__global__ __launch_bounds__(256, 1) void stats3_kernel(const float* __restrict__ xyz, const float* __restrict__ pts,
                                                        const float* __restrict__ outc, const u16* __restrict__ gidx,
                                                        const float* __restrict__ W0f, const float* __restrict__ b0f,
                                                        const float* __restrict__ W1f, const float* __restrict__ b1f,
                                                        const float* __restrict__ W2f, const float* __restrict__ b2f,
                                                        const float* __restrict__ g0, const float* __restrict__ bb0,
                                                        const float* __restrict__ g1, const float* __restrict__ bb1,
                                                        float* __restrict__ stats,
                                                        float* __restrict__ pmax, float* __restrict__ pmin){
    __shared__ float sc1[64], sh1[64], sc2[64], sh2[64];
    __shared__ float tr[256 * 65];
    __shared__ float accs[4][64], accq[4][64];
    if (threadIdx.x < 64){
        bn_coef(stats + 0,   stats + 64,  g0, bb0, threadIdx.x, sc1, sh1);
        bn_coef(stats + 128, stats + 192, g1, bb1, threadIdx.x, sc2, sh2);
    }
    __syncthreads();
    const int row = blockIdx.x * 256 + threadIdx.x;
    float x[9];
    gather_row(xyz, pts, outc, gidx, row, x);
    float x2[64];
    #pragma unroll
    for (int j = 0; j < 64; ++j){
        float acc = b0f[j];
        #pragma unroll
        for (int k = 0; k < 9; ++k) acc = fmaf(x[k], W0f[j*9+k], acc);
        x2[j] = fmaxf(fmaf(acc, sc1[j], sh1[j]), 0.f);
    }
    float x3[64];
    #pragma unroll
    for (int j = 0; j < 64; ++j){
        float a0 = b1f[j], a1 = 0.f, a2 = 0.f, a3 = 0.f;
        const float* wrow = W1f + j * 64;
        #pragma unroll
        for (int k = 0; k < 64; k += 4){
            a0 = fmaf(x2[k+0], wrow[k+0], a0);
            a1 = fmaf(x2[k+1], wrow[k+1], a1);
            a2 = fmaf(x2[k+2], wrow[k+2], a2);
            a3 = fmaf(x2[k+3], wrow[k+3], a3);
        }
        x3[j] = fmaxf(fmaf((a0 + a1) + (a2 + a3), sc2[j], sh2[j]), 0.f);
    }
    const int ch = threadIdx.x & 63, qq = threadIdx.x >> 6;
    for (int half = 0; half < 2; ++half){
        for (int c64 = 0; c64 < 64; ++c64){
            int c = half * 64 + c64;
            float a0 = b2f[c], a1 = 0.f, a2 = 0.f, a3 = 0.f;
            const float* wrow = W2f + c * 64;
            #pragma unroll
            for (int k = 0; k < 64; k += 4){
                a0 = fmaf(x3[k+0], wrow[k+0], a0);
                a1 = fmaf(x3[k+1], wrow[k+1], a1);
                a2 = fmaf(x3[k+2], wrow[k+2], a2);
                a3 = fmaf(x3[k+3], wrow[k+3], a3);
            }
            tr[threadIdx.x * 65 + c64] = (a0 + a1) + (a2 + a3);
        }
        __syncthreads();
        // quarter qq = rows [qq*64, qq*64+64) = groups 2qq (first 32 rows) and 2qq+1
        float s = 0.f, q = 0.f;
        float mxA = -1e30f, mnA = 1e30f, mxB = -1e30f, mnB = 1e30f;
        for (int r = 0; r < 32; ++r){
            float v = tr[(qq * 64 + r) * 65 + ch];
            s += v; q = fmaf(v, v, q);
            mxA = fmaxf(mxA, v); mnA = fminf(mnA, v);
        }
        for (int r = 32; r < 64; ++r){
            float v = tr[(qq * 64 + r) * 65 + ch];
            s += v; q = fmaf(v, v, q);
            mxB = fmaxf(mxB, v); mnB = fminf(mnB, v);
        }
        int c = half * 64 + ch;
        int gA = blockIdx.x * 8 + 2 * qq;
        pmax[(size_t)gA * 128 + c] = mxA;           // coalesced across lanes (c consecutive)
        pmin[(size_t)gA * 128 + c] = mnA;
        pmax[(size_t)(gA + 1) * 128 + c] = mxB;
        pmin[(size_t)(gA + 1) * 128 + c] = mnB;
        accs[qq][ch] = s; accq[qq][ch] = q;
        __syncthreads();
        if (threadIdx.x < 64){
            int cc = half * 64 + threadIdx.x;
            atomicAdd(&stats[256 + cc], (accs[0][threadIdx.x] + accs[1][threadIdx.x])
                                      + (accs[2][threadIdx.x] + accs[3][threadIdx.x]));
        } else if (threadIdx.x < 128){
            int t = threadIdx.x - 64;
            int cc = half * 64 + t;
            atomicAdd(&stats[384 + cc], (accq[0][t] + accq[1][t]) + (accq[2][t] + accq[3][t]));
        }
        __syncthreads();   // tr + accs reuse protection for next half
    }
}

// ---------------- BN3 applied to group max/min, relu, write out region 1 (f32) ----------------
__global__ __launch_bounds__(256) void pool_kernel(const float* __restrict__ stats,
                                                   const float* __restrict__ g2, const float* __restrict__ bb2,
                                                   const float* __restrict__ pmax, const float* __restrict__ pmin,
                                                   float* __restrict__ out){
    __shared__ float sc[128], sh[128];
    if (threadIdx.x < 128) bn_coef(stats + 256, stats + 384, g2, bb2, threadIdx.x, sc, sh);
    __syncthreads();
    int o = blockIdx.x * 256 + threadIdx.x;   // o = g*128 + ch, o < NGRP*128
    int ch = o & 127;
    float a = fmaf(pmax[o], sc[ch], sh[ch]);
    float b = fmaf(pmin[o], sc[ch], sh[ch]);  // affine maps interval endpoints (sc<0 covered)
    out[NGRP * 3 + o] = fmaxf(fmaxf(a, b), 0.0f);
}

extern "C" void kernel_launch(void* const* d_in, const int* in_sizes, int n_in,
                              void* d_out, int out_size, void* d_ws, size_t ws_size,
                              hipStream_t stream){
    const float* xyz = (const float*)d_in[0];
    const float* pts = (const float*)d_in[1];
    const float* W0  = (const float*)d_in[2];
    const float* b0  = (const float*)d_in[3];
    const float* g0  = (const float*)d_in[4];
    const float* bb0 = (const float*)d_in[5];
    const float* W1  = (const float*)d_in[6];
    const float* b1  = (const float*)d_in[7];
    const float* g1  = (const float*)d_in[8];
    const float* bb1 = (const float*)d_in[9];
    const float* W2  = (const float*)d_in[10];
    const float* b2  = (const float*)d_in[11];
    const float* g2  = (const float*)d_in[12];
    const float* bb2 = (const float*)d_in[13];
    float* out = (float*)d_out;   // f32 outputs: [new_xyz 49152 | new_points 2097152]

    // ws layout (bytes): stats[512f]@0 | gidx[524288 u16]@2048 |
    //                    pmax[2097152f]@1050624 | pmin@9439232 ; total 17,827,840
    if (ws_size < 17827840u) return;
    char*  ws    = (char*)d_ws;
    float* stats = (float*)ws;
    u16*   gidx  = (u16*)  (ws + 2048);
    float* pmax  = (float*)(ws + 1050624);
    float* pmin  = (float*)(ws + 9439232);

    zero_kernel <<<1, 512, 0, stream>>>(stats);
    fps_kernel  <<<16, 256, 0, stream>>>(xyz, out);
    ballq_kernel<<<NGRP/4, 256, 0, stream>>>(xyz, out, gidx);
    stats1_kernel<<<ROWS/256, 256, 0, stream>>>(xyz, pts, out, gidx, W0, b0, stats);
    stats2_kernel<<<ROWS/256, 256, 0, stream>>>(xyz, pts, out, gidx, W0, b0, W1, b1, g0, bb0, stats);
    stats3_kernel<<<ROWS/256, 256, 0, stream>>>(xyz, pts, out, gidx, W0, b0, W1, b1, W2, b2,
                                                g0, bb0, g1, bb1, stats, pmax, pmin);
    pool_kernel <<<NGRP*128/256, 256, 0, stream>>>(stats, g2, bb2, pmax, pmin, out);
}